// Round 4
// baseline (210.854 us; speedup 1.0000x reference)
//
#include <hip/hip_runtime.h>
#include <math.h>

#define D_FEAT 128

// bf16 helpers -------------------------------------------------------------
__device__ __forceinline__ unsigned short f2bf(float x) {   // round-nearest-even
    unsigned int b = __float_as_uint(x);
    return (unsigned short)((b + 0x7fffu + ((b >> 16) & 1u)) >> 16);
}
__device__ __forceinline__ float2 bf2_to_f2(unsigned int u) {
    return make_float2(__uint_as_float(u << 16), __uint_as_float(u & 0xffff0000u));
}

// ---------------------------------------------------------------------------
// 1. Fused: (a) normalize rows -> bf16 nfeat + fp32 norm (one wave/node);
//           (b) dst histogram + per-edge rank (the pipeline's ONE atomic pass).
//    Independent tasks on disjoint block ranges — overlaps atomic latency
//    with the BW-bound normalize.
// ---------------------------------------------------------------------------
__global__ void norm_hist_kernel(const float* __restrict__ feat,
                                 const int* __restrict__ dst,
                                 unsigned int* __restrict__ nfb,
                                 float* __restrict__ norm,
                                 int* __restrict__ count,
                                 unsigned short* __restrict__ rank,
                                 int n_nodes, int n_edges, int nb_norm) {
    if ((int)blockIdx.x < nb_norm) {
        int node = (int)(blockIdx.x * blockDim.x + threadIdx.x) >> 6;
        int lane = threadIdx.x & 63;
        if (node >= n_nodes) return;
        float2 f = ((const float2*)feat)[node * 64 + lane];
        float ss = f.x * f.x + f.y * f.y;
        #pragma unroll
        for (int off = 1; off < 64; off <<= 1)
            ss += __shfl_xor(ss, off, 64);
        float nm = fmaxf(sqrtf(ss), 1e-12f);
        float inv = 1.0f / nm;
        unsigned int lo = f2bf(f.x * inv), hi = f2bf(f.y * inv);
        nfb[node * 64 + lane] = (hi << 16) | lo;
        if (lane == 0) norm[node] = nm;
    } else {
        int e = (int)(blockIdx.x - nb_norm) * (int)blockDim.x + (int)threadIdx.x;
        if (e < n_edges)
            rank[e] = (unsigned short)atomicAdd(&count[dst[e]], 1);
    }
}

// ---------------------------------------------------------------------------
// 2. Exclusive scan -> CSR offsets. One 1024-thread block, hierarchical.
// ---------------------------------------------------------------------------
__global__ __launch_bounds__(1024) void scan_kernel(const int* __restrict__ count,
                                                    int* __restrict__ offsets, int n) {
    __shared__ int wsum[16];
    __shared__ int total;
    int t = threadIdx.x;
    const int per = (n + 1023) >> 10;
    int beg = t * per;
    int end = beg + per;
    if (beg > n) beg = n;
    if (end > n) end = n;
    int local[16];
    int s = 0;
    for (int i = beg; i < end; ++i) { int v = count[i]; local[i - beg] = v; s += v; }
    int lane = t & 63, wid = t >> 6;
    int incl = s;
    #pragma unroll
    for (int off = 1; off < 64; off <<= 1) {
        int v = __shfl_up(incl, off, 64);
        if (lane >= off) incl += v;
    }
    if (lane == 63) wsum[wid] = incl;
    __syncthreads();
    if (t == 0) {
        int run = 0;
        #pragma unroll
        for (int w = 0; w < 16; ++w) { int v = wsum[w]; wsum[w] = run; run += v; }
        total = run;
    }
    __syncthreads();
    int base = wsum[wid] + (incl - s);
    for (int i = beg; i < end; ++i) { offsets[i] = base; base += local[i - beg]; }
    if (t == 0) offsets[n] = total;
}

// ---------------------------------------------------------------------------
// 3. Scatter (no atomics, no e-values): src ids only, ushort.
// ---------------------------------------------------------------------------
__global__ void scatter_kernel(const int* __restrict__ src,
                               const int* __restrict__ dst,
                               const int* __restrict__ offsets,
                               const unsigned short* __restrict__ rank,
                               unsigned short* __restrict__ src_sorted,
                               int n_edges) {
    int e = blockIdx.x * blockDim.x + threadIdx.x;
    if (e >= n_edges) return;
    src_sorted[offsets[dst[e]] + (int)rank[e]] = (unsigned short)src[e];
}

// ---------------------------------------------------------------------------
// 4. Fully fused per-node kernel: dot + softmax + aggregation.
//    One wave/node; dst row (bf16x2/lane) in registers. Per 64-edge chunk:
//      pass A: per edge, gather src row (bf16, L2-resident), dot via
//              6-step shuffle reduce -> per-lane ev
//      chunk softmax: one max-reduce + one online rescale
//      pass B: re-gather the same 64 rows (16 KB -> L1 hits) weighted by p.
//    No e-value round trip through memory; dot_rank kernel eliminated.
// ---------------------------------------------------------------------------
__global__ void agg_kernel(const unsigned int* __restrict__ nfb,
                           const float* __restrict__ norm,
                           const float* __restrict__ beta,
                           const int* __restrict__ offsets,
                           const unsigned short* __restrict__ src_sorted,
                           float* __restrict__ out, int n_nodes) {
    int node = (int)(blockIdx.x * blockDim.x + threadIdx.x) >> 6;
    int lane = threadIdx.x & 63;
    if (node >= n_nodes) return;
    int beg = offsets[node];
    int end = offsets[node + 1];
    float2 nd = bf2_to_f2(nfb[node * 64 + lane]);
    float b = beta[0];

    float m = -INFINITY, l = 0.0f, ax = 0.0f, ay = 0.0f;

    for (int base = beg; base < end; base += 64) {
        int nb = end - base;
        if (nb > 64) nb = 64;
        int gi = base + lane;
        bool valid = gi < end;
        int idx = valid ? (int)src_sorted[gi] : 0;
        float nv = norm[idx];

        // pass A: dots for all edges in chunk -> per-lane ev (lane j owns edge j)
        float ev = -INFINITY;
        for (int j = 0; j < nb; ++j) {
            int sj = __shfl(idx, j, 64);
            float2 f = bf2_to_f2(nfb[sj * 64 + lane]);
            float part = f.x * nd.x + f.y * nd.y;
            #pragma unroll
            for (int off = 1; off < 64; off <<= 1)
                part += __shfl_xor(part, off, 64);
            if (lane == j) ev = part;
        }
        ev = valid ? b * ev : -INFINITY;

        // chunk max -> single online rescale
        float cm = ev;
        #pragma unroll
        for (int off = 1; off < 64; off <<= 1)
            cm = fmaxf(cm, __shfl_xor(cm, off, 64));
        float m2 = fmaxf(m, cm);
        float scale = expf(m - m2);   // first chunk: exp(-inf) = 0
        ax *= scale; ay *= scale; l *= scale;
        m = m2;

        float pe = expf(ev - m);      // 0 for invalid lanes
        l += pe;                      // per-lane partial denom (reduced at end)
        float pv = pe * nv;

        // pass B: weighted accumulation (rows are L1-hot from pass A)
        for (int j = 0; j < nb; ++j) {
            float wj = __shfl(pv, j, 64);
            int sj = __shfl(idx, j, 64);
            float2 f = bf2_to_f2(nfb[sj * 64 + lane]);
            ax += wj * f.x;
            ay += wj * f.y;
        }
    }
    #pragma unroll
    for (int off = 1; off < 64; off <<= 1)
        l += __shfl_xor(l, off, 64);
    float invl = (l > 0.0f) ? (1.0f / l) : 0.0f;
    ((float2*)out)[node * 64 + lane] = make_float2(ax * invl, ay * invl);
}

// ---------------------------------------------------------------------------
extern "C" void kernel_launch(void* const* d_in, const int* in_sizes, int n_in,
                              void* d_out, int out_size, void* d_ws, size_t ws_size,
                              hipStream_t stream) {
    const float* feat = (const float*)d_in[0];
    const int* src    = (const int*)d_in[1];
    const int* dst    = (const int*)d_in[2];
    const float* beta = (const float*)d_in[3];
    float* out = (float*)d_out;

    const int n_nodes = in_sizes[0] / D_FEAT;
    const int n_edges = in_sizes[1];

    char* ws = (char*)d_ws;
    size_t off = 0;
    auto alloc = [&](size_t bytes) -> void* {
        void* p = ws + off;
        off += (bytes + 255) & ~(size_t)255;
        return p;
    };
    unsigned int*   nfb        = (unsigned int*)alloc((size_t)n_nodes * 64 * 4); // 2.56 MB bf16x2
    float*          norm       = (float*)alloc((size_t)n_nodes * 4);
    int*            count      = (int*)  alloc((size_t)n_nodes * 4);
    int*            offsets    = (int*)  alloc((size_t)(n_nodes + 1) * 4);
    unsigned short* rank       = (unsigned short*)alloc((size_t)n_edges * 2);    // 1.28 MB
    unsigned short* src_sorted = (unsigned short*)alloc((size_t)n_edges * 2);    // 1.28 MB

    hipMemsetAsync(count, 0, (size_t)n_nodes * sizeof(int), stream);

    int nb_norm = (n_nodes * 64 + 255) / 256;
    int nb_hist = (n_edges + 255) / 256;
    norm_hist_kernel<<<nb_norm + nb_hist, 256, 0, stream>>>(
        feat, dst, nfb, norm, count, rank, n_nodes, n_edges, nb_norm);

    scan_kernel<<<1, 1024, 0, stream>>>(count, offsets, n_nodes);

    scatter_kernel<<<(n_edges + 255) / 256, 256, 0, stream>>>(
        src, dst, offsets, rank, src_sorted, n_edges);

    agg_kernel<<<(n_nodes + 3) / 4, 256, 0, stream>>>(
        nfb, norm, beta, offsets, src_sorted, out, n_nodes);
}

// Round 6
// 171.721 us; speedup vs baseline: 1.2279x; 1.2279x over previous
//
#include <hip/hip_runtime.h>
#include <math.h>

#define D_FEAT 128

// bf16 helpers -------------------------------------------------------------
__device__ __forceinline__ unsigned short f2bf(float x) {   // round-nearest-even
    unsigned int b = __float_as_uint(x);
    return (unsigned short)((b + 0x7fffu + ((b >> 16) & 1u)) >> 16);
}
__device__ __forceinline__ float2 bf2_to_f2(unsigned int u) {
    return make_float2(__uint_as_float(u << 16), __uint_as_float(u & 0xffff0000u));
}
__device__ __forceinline__ float dot_bf2(unsigned int a, unsigned int b) {
    float2 fa = bf2_to_f2(a), fb = bf2_to_f2(b);
    return fa.x * fb.x + fa.y * fb.y;
}

// ---------------------------------------------------------------------------
// 1. Fused: (a) normalize rows -> bf16 nfeat (uint = 2 dims) + fp32 norm;
//           (b) dst histogram + per-edge rank (the pipeline's ONE atomic pass).
//    Disjoint block ranges; atomic latency overlaps the BW-bound normalize.
// ---------------------------------------------------------------------------
__global__ void norm_hist_kernel(const float* __restrict__ feat,
                                 const int* __restrict__ dst,
                                 unsigned int* __restrict__ nfb,
                                 float* __restrict__ norm,
                                 int* __restrict__ count,
                                 unsigned short* __restrict__ rank,
                                 int n_nodes, int n_edges, int nb_norm) {
    if ((int)blockIdx.x < nb_norm) {
        int node = (int)(blockIdx.x * blockDim.x + threadIdx.x) >> 6;
        int lane = threadIdx.x & 63;
        if (node >= n_nodes) return;
        float2 f = ((const float2*)feat)[node * 64 + lane];
        float ss = f.x * f.x + f.y * f.y;
        #pragma unroll
        for (int off = 1; off < 64; off <<= 1)
            ss += __shfl_xor(ss, off, 64);
        float nm = fmaxf(sqrtf(ss), 1e-12f);
        float inv = 1.0f / nm;
        unsigned int lo = f2bf(f.x * inv), hi = f2bf(f.y * inv);
        nfb[node * 64 + lane] = (hi << 16) | lo;
        if (lane == 0) norm[node] = nm;
    } else {
        int e = (int)(blockIdx.x - nb_norm) * (int)blockDim.x + (int)threadIdx.x;
        if (e < n_edges)
            rank[e] = (unsigned short)atomicAdd(&count[dst[e]], 1);
    }
}

// ---------------------------------------------------------------------------
// 2. Exclusive scan -> CSR offsets. One 1024-thread block, hierarchical.
// ---------------------------------------------------------------------------
__global__ __launch_bounds__(1024) void scan_kernel(const int* __restrict__ count,
                                                    int* __restrict__ offsets, int n) {
    __shared__ int wsum[16];
    __shared__ int total;
    int t = threadIdx.x;
    const int per = (n + 1023) >> 10;
    int beg = t * per;
    int end = beg + per;
    if (beg > n) beg = n;
    if (end > n) end = n;
    int local[16];
    int s = 0;
    for (int i = beg; i < end; ++i) { int v = count[i]; local[i - beg] = v; s += v; }
    int lane = t & 63, wid = t >> 6;
    int incl = s;
    #pragma unroll
    for (int off = 1; off < 64; off <<= 1) {
        int v = __shfl_up(incl, off, 64);
        if (lane >= off) incl += v;
    }
    if (lane == 63) wsum[wid] = incl;
    __syncthreads();
    if (t == 0) {
        int run = 0;
        #pragma unroll
        for (int w = 0; w < 16; ++w) { int v = wsum[w]; wsum[w] = run; run += v; }
        total = run;
    }
    __syncthreads();
    int base = wsum[wid] + (incl - s);
    for (int i = beg; i < end; ++i) { offsets[i] = base; base += local[i - beg]; }
    if (t == 0) offsets[n] = total;
}

// ---------------------------------------------------------------------------
// 3. Fused dot + scatter: 8 lanes per edge, bf16 rows (L2-resident).
//    Each lane reads 2x uint4 per row (8 lanes x 16 dims = 128), explicit
//    component FMA (NO pointer punning across locals — round-5 bug), 3-step
//    sub-group reduce. Leader writes src id + raw dot at the CSR position.
// ---------------------------------------------------------------------------
__global__ void dot_scatter_kernel(const unsigned int* __restrict__ nfb,
                                   const int* __restrict__ src,
                                   const int* __restrict__ dst,
                                   const int* __restrict__ offsets,
                                   const unsigned short* __restrict__ rank,
                                   unsigned short* __restrict__ src_sorted,
                                   float* __restrict__ e_sorted,
                                   int n_edges) {
    int gtid = blockIdx.x * blockDim.x + threadIdx.x;
    int edge = gtid >> 3;
    int r = threadIdx.x & 7;
    if (edge >= n_edges) return;
    int s = src[edge];
    int d = dst[edge];
    const uint4* pa = (const uint4*)(nfb + (size_t)s * 64);
    const uint4* pb = (const uint4*)(nfb + (size_t)d * 64);
    uint4 a0 = pa[r], a1 = pa[r + 8];
    uint4 b0 = pb[r], b1 = pb[r + 8];
    float part = 0.0f;
    part += dot_bf2(a0.x, b0.x);
    part += dot_bf2(a0.y, b0.y);
    part += dot_bf2(a0.z, b0.z);
    part += dot_bf2(a0.w, b0.w);
    part += dot_bf2(a1.x, b1.x);
    part += dot_bf2(a1.y, b1.y);
    part += dot_bf2(a1.z, b1.z);
    part += dot_bf2(a1.w, b1.w);
    #pragma unroll
    for (int off = 1; off < 8; off <<= 1)
        part += __shfl_xor(part, off, 8);
    if (r == 0) {
        int pos = offsets[d] + (int)rank[edge];
        src_sorted[pos] = (unsigned short)s;
        e_sorted[pos] = part;
    }
}

// ---------------------------------------------------------------------------
// 4. Per-node softmax + aggregation. One wave per node. Per 64-edge chunk:
//    lane i owns edge base+i (coalesced e/src loads), ONE wave max-reduce +
//    ONE online rescale, exp computed once per lane IN PARALLEL, then a lean
//    ~6-slot/edge inner loop: 2 shuffles + 1 dword bf16 load + unpack + 2 FMA.
// ---------------------------------------------------------------------------
__global__ void agg_kernel(const unsigned int* __restrict__ nfb,
                           const float* __restrict__ norm,
                           const float* __restrict__ beta,
                           const int* __restrict__ offsets,
                           const unsigned short* __restrict__ src_sorted,
                           const float* __restrict__ e_sorted,
                           float* __restrict__ out, int n_nodes) {
    int node = (int)(blockIdx.x * blockDim.x + threadIdx.x) >> 6;
    int lane = threadIdx.x & 63;
    if (node >= n_nodes) return;
    int beg = offsets[node];
    int end = offsets[node + 1];
    float b = beta[0];

    float m = -INFINITY, l = 0.0f, ax = 0.0f, ay = 0.0f;

    for (int base = beg; base < end; base += 64) {
        int nb = end - base;
        if (nb > 64) nb = 64;
        int gi = base + lane;
        bool valid = gi < end;
        int idx = valid ? (int)src_sorted[gi] : 0;
        float ev = valid ? b * e_sorted[gi] : -INFINITY;
        float nv = norm[idx];

        // chunk max -> single online rescale
        float cm = ev;
        #pragma unroll
        for (int off = 1; off < 64; off <<= 1)
            cm = fmaxf(cm, __shfl_xor(cm, off, 64));
        float m2 = fmaxf(m, cm);
        float scale = expf(m - m2);   // first chunk: exp(-inf) = 0
        ax *= scale; ay *= scale; l *= scale;
        m = m2;

        float pe = expf(ev - m);      // parallel: one exp per lane = per edge
        l += pe;                      // per-lane partial denom, reduced at end
        float pv = pe * nv;

        #pragma unroll 8
        for (int j = 0; j < nb; ++j) {
            float wj = __shfl(pv, j, 64);
            int sj = __shfl(idx, j, 64);
            float2 f = bf2_to_f2(nfb[sj * 64 + lane]);
            ax += wj * f.x;
            ay += wj * f.y;
        }
    }
    #pragma unroll
    for (int off = 1; off < 64; off <<= 1)
        l += __shfl_xor(l, off, 64);
    float invl = (l > 0.0f) ? (1.0f / l) : 0.0f;
    ((float2*)out)[node * 64 + lane] = make_float2(ax * invl, ay * invl);
}

// ---------------------------------------------------------------------------
extern "C" void kernel_launch(void* const* d_in, const int* in_sizes, int n_in,
                              void* d_out, int out_size, void* d_ws, size_t ws_size,
                              hipStream_t stream) {
    const float* feat = (const float*)d_in[0];
    const int* src    = (const int*)d_in[1];
    const int* dst    = (const int*)d_in[2];
    const float* beta = (const float*)d_in[3];
    float* out = (float*)d_out;

    const int n_nodes = in_sizes[0] / D_FEAT;
    const int n_edges = in_sizes[1];

    char* ws = (char*)d_ws;
    size_t off = 0;
    auto alloc = [&](size_t bytes) -> void* {
        void* p = ws + off;
        off += (bytes + 255) & ~(size_t)255;
        return p;
    };
    unsigned int*   nfb        = (unsigned int*)alloc((size_t)n_nodes * 64 * 4); // 2.56 MB
    float*          norm       = (float*)alloc((size_t)n_nodes * 4);
    int*            count      = (int*)  alloc((size_t)n_nodes * 4);
    int*            offsets    = (int*)  alloc((size_t)(n_nodes + 1) * 4);
    unsigned short* rank       = (unsigned short*)alloc((size_t)n_edges * 2);    // 1.28 MB
    unsigned short* src_sorted = (unsigned short*)alloc((size_t)n_edges * 2);    // 1.28 MB
    float*          e_sorted   = (float*)alloc((size_t)n_edges * 4);             // 2.56 MB

    hipMemsetAsync(count, 0, (size_t)n_nodes * sizeof(int), stream);

    int nb_norm = (n_nodes * 64 + 255) / 256;
    int nb_hist = (n_edges + 255) / 256;
    norm_hist_kernel<<<nb_norm + nb_hist, 256, 0, stream>>>(
        feat, dst, nfb, norm, count, rank, n_nodes, n_edges, nb_norm);

    scan_kernel<<<1, 1024, 0, stream>>>(count, offsets, n_nodes);

    int ds_blocks = (int)(((size_t)n_edges * 8 + 255) / 256);
    dot_scatter_kernel<<<ds_blocks, 256, 0, stream>>>(
        nfb, src, dst, offsets, rank, src_sorted, e_sorted, n_edges);

    agg_kernel<<<(n_nodes + 3) / 4, 256, 0, stream>>>(
        nfb, norm, beta, offsets, src_sorted, e_sorted, out, n_nodes);
}